// Round 8
// baseline (128.868 us; speedup 1.0000x reference)
//
#include <hip/hip_runtime.h>

typedef short bf16x8 __attribute__((ext_vector_type(8)));
typedef float f32x4 __attribute__((ext_vector_type(4)));
typedef unsigned int u32;
typedef __attribute__((address_space(1))) const u32 gu32;
typedef __attribute__((address_space(3))) u32 lu32;

#define NEG_INF (-__builtin_inff())

static __device__ __forceinline__ unsigned short f2bf(float f) {
  union { float f; unsigned u; } v; v.f = f;
  return (unsigned short)((v.u + 0x7fffu + ((v.u >> 16) & 1u)) >> 16);
}
static __device__ __forceinline__ unsigned fbits(float f) {
  union { float f; unsigned u; } v; v.f = f;
  return v.u;
}
// pack two floats to packed bf16 (round-half-up): low16 = a, high16 = b
static __device__ __forceinline__ unsigned pack2(float a, float b) {
  return __builtin_amdgcn_perm(fbits(b) + 0x8000u, fbits(a) + 0x8000u, 0x07060302u);
}
static __device__ __forceinline__ f32x4 mfma16(bf16x8 a, bf16x8 b, f32x4 c) {
  return __builtin_amdgcn_mfma_f32_16x16x32_bf16(a, b, c, 0, 0, 0);
}
// async DMA: 64 lanes x 16B -> contiguous 1KB LDS at (uniform) l + lane*16
static __device__ __forceinline__ void dma16(const void* g, void* l) {
  __builtin_amdgcn_global_load_lds((gu32*)g, (lu32*)l, 16, 0, 0);
}

// ---------------- kernel 0: W -> swizzled-tiled W^T chunks ----------------
// layout: [chunk c6=c>>6][row dd (0..191: Q,K,V x 64)][64 c], byte =
// (c6*192+dd)*128 + ((cin*2) ^ ((dd&7)<<4)).  Q rows pre-scaled by 0.125*log2(e).
__global__ __launch_bounds__(256) void prep_w(const float* __restrict__ wq,
                                              const float* __restrict__ wk,
                                              const float* __restrict__ wv,
                                              char* __restrict__ wt) {
  int i = blockIdx.x * 256 + threadIdx.x;
  if (i >= 384 * 64) return;
  int c = i >> 6, d = i & 63;
  int c6 = c >> 6, cin = c & 63;
  const float Cs = 0.18033688011112042f;
  long base = (long)(c6 * 192) * 128;
  int col = (cin * 2) ^ ((d & 7) << 4);
  *(unsigned short*)(wt + base + (long)d * 128 + col) = f2bf(wq[i] * Cs);
  *(unsigned short*)(wt + base + (long)(64 + d) * 128 + col) = f2bf(wk[i]);
  *(unsigned short*)(wt + base + (long)(128 + d) * 128 + col) = f2bf(wv[i]);
}

// ---------------- kernel 1: QKV projection ----------------
// 512 blocks x 4 waves (64 tokens/block, 16/wave). W staged to LDS by 24KB
// chunks via global_load_lds (double-buffered); x held in registers.
// Q,K use mfma16(wf, axk): C[m=d][n=token] -> lane's 4 values span consecutive
// d at fixed token -> one 8B store per nt. V uses mfma16(axk, wf):
// C[m=token][n=d] -> values span tokens along the V^T row -> 8B store.
// Outputs: Q plain [tok][64]; K tiled-swizzled [b][kt][key][64d];
// V^T tiled-swizzled [b][kt][d][64key].
__global__ __launch_bounds__(256, 2) void proj_kernel(
    const float* __restrict__ x, const char* __restrict__ wt,
    unsigned short* __restrict__ qo, char* __restrict__ kT,
    char* __restrict__ vT) {
  __shared__ char wls[2][24576];
  const int tid = threadIdx.x;
  const int wave = tid >> 6, lane = tid & 63;
  const int lo = lane & 15, quad = lane >> 4;
  const long tok0 = ((long)blockIdx.x * 4 + wave) * 16;

  // prologue: DMA chunk 0 (24 segs of 1KB; wave issues segs wave*6..wave*6+5)
#pragma unroll
  for (int s2 = 0; s2 < 6; ++s2) {
    const int s = wave * 6 + s2;
    dma16(wt + s * 1024 + lane * 16, &wls[0][s * 1024]);
  }
  // x fragments -> registers (the only HBM read)
  bf16x8 ax[12];
  const float* xr = x + (tok0 + lo) * 384 + quad * 8;
#pragma unroll
  for (int kk = 0; kk < 12; ++kk) {
    float4 x0 = *(const float4*)(xr + kk * 32);
    float4 x1 = *(const float4*)(xr + kk * 32 + 4);
    bf16x8 a;
    a[0] = (short)f2bf(x0.x); a[1] = (short)f2bf(x0.y);
    a[2] = (short)f2bf(x0.z); a[3] = (short)f2bf(x0.w);
    a[4] = (short)f2bf(x1.x); a[5] = (short)f2bf(x1.y);
    a[6] = (short)f2bf(x1.z); a[7] = (short)f2bf(x1.w);
    ax[kk] = a;
  }

  f32x4 acc[12];
#pragma unroll
  for (int nt = 0; nt < 12; ++nt) acc[nt] = (f32x4){0.f, 0.f, 0.f, 0.f};

  for (int c6 = 0; c6 < 6; ++c6) {
    const int buf = c6 & 1;
    __syncthreads();                       // chunk c6 resident; buf^1 free
    if (c6 < 5) {
      const char* wg = wt + (long)(c6 + 1) * 24576;
#pragma unroll
      for (int s2 = 0; s2 < 6; ++s2) {
        const int s = wave * 6 + s2;
        dma16(wg + s * 1024 + lane * 16, &wls[buf ^ 1][s * 1024]);
      }
    }
#pragma unroll
    for (int kk = 0; kk < 2; ++kk) {
      const bf16x8 axk = ax[c6 * 2 + kk];
#pragma unroll
      for (int nt = 0; nt < 12; ++nt) {
        const int dd = nt * 16 + lo;
        const int col = ((kk * 4 + quad) ^ (lo & 7)) << 4;
        bf16x8 wf = *(const bf16x8*)(&wls[buf][dd * 128 + col]);
        if (nt < 8)
          acc[nt] = mfma16(wf, axk, acc[nt]);   // C[d][token]
        else
          acc[nt] = mfma16(axk, wf, acc[nt]);   // C[token][d]
      }
    }
  }

  // epilogue: one 8-byte store per nt
  const long bb = tok0 >> 11;
  const int tin0 = (int)(tok0 & 2047);
  const int kt = tin0 >> 6;
  const long tile = ((bb * 32 + kt) << 13);   // 8192 B per tile
  const int key0w = (tin0 & 63) + quad * 4;   // V: token_local of acc rows r=0..3
  const int keyl = (tin0 & 63) + lo;          // Q/K: this lane's token
#pragma unroll
  for (int nt = 0; nt < 12; ++nt) {
    uint2 uu;
    uu.x = pack2(acc[nt][0], acc[nt][1]);
    uu.y = pack2(acc[nt][2], acc[nt][3]);
    if (nt < 4) {
      // Q[tok0+lo][nt*16+quad*4 .. +3]
      *(uint2*)(qo + (tok0 + lo) * 64 + nt * 16 + quad * 4) = uu;
    } else if (nt < 8) {
      // K tile row = key (token), cols d0..d0+3 (swizzled granule)
      const int d0 = (nt - 4) * 16 + quad * 4;
      *(uint2*)(kT + tile + keyl * 128 + (((d0 * 2) ^ ((keyl & 7) << 4)))) = uu;
    } else {
      // V^T row d, cols = tokens key0w..key0w+3 (swizzled granule)
      const int d = (nt - 8) * 16 + lo;
      *(uint2*)(vT + tile + d * 128 + (((key0w * 2) ^ ((d & 7) << 4)))) = uu;
    }
  }
}

// ---------------- kernel 2: causal flash attention, shared-LDS K/V ----------------
// 512 blocks x 4 waves. Block = (64-q-row group a, batch b); wave w owns q-tile
// j=4a+w. All waves share the same a+1 key tiles, DMA'd to LDS double-buffered.
// Pairing: blocks i and i+256 have a-sums 31 (uniform per-CU load).
__global__ __launch_bounds__(256, 2) void attn_kernel(
    const unsigned short* __restrict__ qg, const char* __restrict__ kT,
    const char* __restrict__ vT, float* __restrict__ out) {
  __shared__ char kls[2][8192];
  __shared__ char vls[2][8192];
  __shared__ unsigned short ps[4][16][72];  // wave-private P^T [qrow][key]

  const int tid = threadIdx.x;
  const int h = tid >> 6, lane = tid & 63;
  const int lo = lane & 15, quad = lane >> 4;
  const int b = blockIdx.x & 15;
  const int idx = blockIdx.x >> 4;
  const int a = (blockIdx.x < 256) ? (31 - idx) : (idx - 16);
  const int j = 4 * a + h;
  const int niter = a + 1;
  const int qrow0 = j * 16;

  const unsigned short* qb = qg + (long)b * 2048 * 64;
  const char* kbT = kT + ((long)b * 32 << 13);
  const char* vbT = vT + ((long)b * 32 << 13);
  float* ob = out + (long)b * 2048 * 64;

  // Q fragments (B-operand), pre-scaled by 0.125*log2(e)
  const unsigned short* qr = qb + (long)(qrow0 + lo) * 64 + quad * 8;
  const bf16x8 bq0 = *(const bf16x8*)qr;
  const bf16x8 bq1 = *(const bf16x8*)(qr + 32);

  // prologue DMA: tile 0 -> buf 0 (wave h issues segs 2h, 2h+1 of K and V)
#pragma unroll
  for (int s2 = 0; s2 < 2; ++s2) {
    const int s = h * 2 + s2;
    dma16(kbT + s * 1024 + lane * 16, &kls[0][s * 1024]);
    dma16(vbT + s * 1024 + lane * 16, &vls[0][s * 1024]);
  }

  f32x4 oacc[4];
#pragma unroll
  for (int dt = 0; dt < 4; ++dt) oacc[dt] = (f32x4){0.f, 0.f, 0.f, 0.f};
  float l = 0.f;

  for (int kt = 0; kt < niter; ++kt) {
    const int buf = kt & 1;
    __syncthreads();  // tile kt resident (vmcnt drained); buf^1 consumers done
    if (kt + 1 < niter) {
      const char* kg = kbT + ((long)(kt + 1) << 13);
      const char* vg = vbT + ((long)(kt + 1) << 13);
#pragma unroll
      for (int s2 = 0; s2 < 2; ++s2) {
        const int s = h * 2 + s2;
        dma16(kg + s * 1024 + lane * 16, &kls[buf ^ 1][s * 1024]);
        dma16(vg + s * 1024 + lane * 16, &vls[buf ^ 1][s * 1024]);
      }
    }
    const bool diag = (kt == niter - 1);
    const int key0 = kt * 64;
    const int swz = (lo & 7);

    // per-16-key strip: QK -> mask -> exp2 -> pack -> ps
#pragma unroll
    for (int t = 0; t < 4; ++t) {
      const int row = (t * 16 + lo) * 128;
      bf16x8 ak0 = *(const bf16x8*)(&kls[buf][row + ((quad ^ swz) << 4)]);
      bf16x8 ak1 = *(const bf16x8*)(&kls[buf][row + (((4 + quad) ^ swz) << 4)]);
      f32x4 s = (f32x4){0.f, 0.f, 0.f, 0.f};
      s = mfma16(ak0, bq0, s);
      s = mfma16(ak1, bq1, s);
      if (diag) {
        const int qrl = qrow0 + lo;
#pragma unroll
        for (int r = 0; r < 4; ++r)
          if (key0 + t * 16 + quad * 4 + r > qrl) s[r] = NEG_INF;
      }
      float e0 = __builtin_amdgcn_exp2f(s[0]);
      float e1 = __builtin_amdgcn_exp2f(s[1]);
      float e2 = __builtin_amdgcn_exp2f(s[2]);
      float e3 = __builtin_amdgcn_exp2f(s[3]);
      l += (e0 + e1) + (e2 + e3);
      uint2 uu;
      uu.x = pack2(e0, e1);
      uu.y = pack2(e2, e3);
      *(uint2*)&ps[h][lo][t * 16 + quad * 4] = uu;
    }
    asm volatile("s_waitcnt lgkmcnt(0)" ::: "memory");  // wave-private ps
    // O^T += V^T P^T
#pragma unroll
    for (int kk2 = 0; kk2 < 2; ++kk2) {
      bf16x8 bp = *(const bf16x8*)&ps[h][lo][kk2 * 32 + quad * 8];
#pragma unroll
      for (int dt = 0; dt < 4; ++dt) {
        const int rowv = (dt * 16 + lo) * 128;
        bf16x8 av = *(const bf16x8*)(&vls[buf][rowv + (((kk2 * 4 + quad) ^ swz) << 4)]);
        oacc[dt] = mfma16(av, bp, oacc[dt]);
      }
    }
  }

  // epilogue: per-wave complete rows — reduce l over quads, normalize, store
  l += __shfl_xor(l, 16, 64);
  l += __shfl_xor(l, 32, 64);
  const float inv = 1.0f / l;
  float* orow = ob + (long)(qrow0 + lo) * 64;
#pragma unroll
  for (int dt = 0; dt < 4; ++dt) {
    float4 st;
    st.x = oacc[dt][0] * inv; st.y = oacc[dt][1] * inv;
    st.z = oacc[dt][2] * inv; st.w = oacc[dt][3] * inv;
    *(float4*)(orow + dt * 16 + quad * 4) = st;
  }
}

// ---------------- launcher ----------------
extern "C" void kernel_launch(void* const* d_in, const int* in_sizes, int n_in,
                              void* d_out, int out_size, void* d_ws, size_t ws_size,
                              hipStream_t stream) {
  const float* x = (const float*)d_in[0];
  const float* wq = (const float*)d_in[1];
  const float* wk = (const float*)d_in[2];
  const float* wv = (const float*)d_in[3];
  float* out = (float*)d_out;

  char* ws = (char*)d_ws;
  char* wt = ws;                                   // 147456 B (6 chunks x 24576)
  const size_t MB4 = (size_t)4 * 1024 * 1024;      // 16*2048*64*2 bytes
  unsigned short* qws = (unsigned short*)(ws + 147456);
  char* kT = ws + 147456 + MB4;
  char* vT = ws + 147456 + 2 * MB4;

  prep_w<<<96, 256, 0, stream>>>(wq, wk, wv, wt);
  proj_kernel<<<512, 256, 0, stream>>>(x, wt, qws, kT, vT);
  attn_kernel<<<512, 256, 0, stream>>>(qws, kT, vT, out);
}

// Round 9
// 127.037 us; speedup vs baseline: 1.0144x; 1.0144x over previous
//
#include <hip/hip_runtime.h>

typedef short bf16x8 __attribute__((ext_vector_type(8)));
typedef float f32x4 __attribute__((ext_vector_type(4)));
typedef unsigned int u32;
typedef __attribute__((address_space(1))) const u32 gu32;
typedef __attribute__((address_space(3))) u32 lu32;

#define NEG_INF (-__builtin_inff())

static __device__ __forceinline__ unsigned short f2bf(float f) {
  union { float f; unsigned u; } v; v.f = f;
  return (unsigned short)((v.u + 0x7fffu + ((v.u >> 16) & 1u)) >> 16);
}
static __device__ __forceinline__ unsigned fbits(float f) {
  union { float f; unsigned u; } v; v.f = f;
  return v.u;
}
// pack two floats to packed bf16 (round-half-up): low16 = a, high16 = b
static __device__ __forceinline__ unsigned pack2(float a, float b) {
  return __builtin_amdgcn_perm(fbits(b) + 0x8000u, fbits(a) + 0x8000u, 0x07060302u);
}
static __device__ __forceinline__ f32x4 mfma16(bf16x8 a, bf16x8 b, f32x4 c) {
  return __builtin_amdgcn_mfma_f32_16x16x32_bf16(a, b, c, 0, 0, 0);
}
// async DMA: 64 lanes x 16B -> contiguous 1KB LDS at (uniform) l + lane*16
static __device__ __forceinline__ void dma16(const void* g, void* l) {
  __builtin_amdgcn_global_load_lds((gu32*)g, (lu32*)l, 16, 0, 0);
}

// ---------------- kernel 0: W -> swizzled-tiled W^T chunks ----------------
// layout: [chunk c6=c>>6][row dd (0..191: Q,K,V x 64)][64 c], byte =
// (c6*192+dd)*128 + ((cin*2) ^ ((dd&7)<<4)).  Q rows pre-scaled by 0.125*log2(e).
__global__ __launch_bounds__(256) void prep_w(const float* __restrict__ wq,
                                              const float* __restrict__ wk,
                                              const float* __restrict__ wv,
                                              char* __restrict__ wt) {
  int i = blockIdx.x * 256 + threadIdx.x;
  if (i >= 384 * 64) return;
  int c = i >> 6, d = i & 63;
  int c6 = c >> 6, cin = c & 63;
  const float Cs = 0.18033688011112042f;
  long base = (long)(c6 * 192) * 128;
  int col = (cin * 2) ^ ((d & 7) << 4);
  *(unsigned short*)(wt + base + (long)d * 128 + col) = f2bf(wq[i] * Cs);
  *(unsigned short*)(wt + base + (long)(64 + d) * 128 + col) = f2bf(wk[i]);
  *(unsigned short*)(wt + base + (long)(128 + d) * 128 + col) = f2bf(wv[i]);
}

// ---------------- kernel 1: QKV projection ----------------
// 512 blocks x 4 waves (64 tokens/block, 16/wave). W staged to LDS by 24KB
// chunks via global_load_lds (double-buffered); x held in registers.
// Q,K use mfma16(wf, axk): C[m=d][n=token]; V uses mfma16(axk, wf): C[m=token][n=d].
// Outputs: Q plain [tok][64]; K tiled-swizzled [b][kt][key][64d];
// V^T tiled-swizzled [b][kt][d][64key].
__global__ __launch_bounds__(256, 2) void proj_kernel(
    const float* __restrict__ x, const char* __restrict__ wt,
    unsigned short* __restrict__ qo, char* __restrict__ kT,
    char* __restrict__ vT) {
  __shared__ char wls[2][24576];
  const int tid = threadIdx.x;
  const int wave = tid >> 6, lane = tid & 63;
  const int lo = lane & 15, quad = lane >> 4;
  const long tok0 = ((long)blockIdx.x * 4 + wave) * 16;

  // prologue: DMA chunk 0 (24 segs of 1KB; wave issues segs wave*6..wave*6+5)
#pragma unroll
  for (int s2 = 0; s2 < 6; ++s2) {
    const int s = wave * 6 + s2;
    dma16(wt + s * 1024 + lane * 16, &wls[0][s * 1024]);
  }
  // x fragments -> registers (the only HBM read)
  bf16x8 ax[12];
  const float* xr = x + (tok0 + lo) * 384 + quad * 8;
#pragma unroll
  for (int kk = 0; kk < 12; ++kk) {
    float4 x0 = *(const float4*)(xr + kk * 32);
    float4 x1 = *(const float4*)(xr + kk * 32 + 4);
    bf16x8 a;
    a[0] = (short)f2bf(x0.x); a[1] = (short)f2bf(x0.y);
    a[2] = (short)f2bf(x0.z); a[3] = (short)f2bf(x0.w);
    a[4] = (short)f2bf(x1.x); a[5] = (short)f2bf(x1.y);
    a[6] = (short)f2bf(x1.z); a[7] = (short)f2bf(x1.w);
    ax[kk] = a;
  }

  f32x4 acc[12];
#pragma unroll
  for (int nt = 0; nt < 12; ++nt) acc[nt] = (f32x4){0.f, 0.f, 0.f, 0.f};

  for (int c6 = 0; c6 < 6; ++c6) {
    const int buf = c6 & 1;
    __syncthreads();                       // chunk c6 resident; buf^1 free
    if (c6 < 5) {
      const char* wg = wt + (long)(c6 + 1) * 24576;
#pragma unroll
      for (int s2 = 0; s2 < 6; ++s2) {
        const int s = wave * 6 + s2;
        dma16(wg + s * 1024 + lane * 16, &wls[buf ^ 1][s * 1024]);
      }
    }
#pragma unroll
    for (int kk = 0; kk < 2; ++kk) {
      const bf16x8 axk = ax[c6 * 2 + kk];
#pragma unroll
      for (int nt = 0; nt < 12; ++nt) {
        const int dd = nt * 16 + lo;
        const int col = ((kk * 4 + quad) ^ (lo & 7)) << 4;
        bf16x8 wf = *(const bf16x8*)(&wls[buf][dd * 128 + col]);
        if (nt < 8)
          acc[nt] = mfma16(wf, axk, acc[nt]);   // C[d][token]
        else
          acc[nt] = mfma16(axk, wf, acc[nt]);   // C[token][d]
      }
    }
  }

  // epilogue: one 8-byte store per nt
  const long bb = tok0 >> 11;
  const int tin0 = (int)(tok0 & 2047);
  const int kt = tin0 >> 6;
  const long tile = ((bb * 32 + kt) << 13);   // 8192 B per tile
  const int key0w = (tin0 & 63) + quad * 4;   // V: token_local of acc rows r=0..3
  const int keyl = (tin0 & 63) + lo;          // Q/K: this lane's token
#pragma unroll
  for (int nt = 0; nt < 12; ++nt) {
    uint2 uu;
    uu.x = pack2(acc[nt][0], acc[nt][1]);
    uu.y = pack2(acc[nt][2], acc[nt][3]);
    if (nt < 4) {
      *(uint2*)(qo + (tok0 + lo) * 64 + nt * 16 + quad * 4) = uu;
    } else if (nt < 8) {
      const int d0 = (nt - 4) * 16 + quad * 4;
      *(uint2*)(kT + tile + keyl * 128 + (((d0 * 2) ^ ((keyl & 7) << 4)))) = uu;
    } else {
      const int d = (nt - 8) * 16 + lo;
      *(uint2*)(vT + tile + d * 128 + (((key0w * 2) ^ ((d & 7) << 4)))) = uu;
    }
  }
}

// ---------------- kernel 2: causal flash attention, shared-LDS K/V ----------------
// 512 blocks x 4 waves. Block = (64-q-row group a, batch b); wave w owns q-tile
// j=4a+w. Key tiles staged 2-per-barrier (32KB/stage, double-buffered) to halve
// barrier-drain count vs R7 (17 vs 33 barriers at a=31) and double DMA prefetch
// distance. Conditional 2nd-tile compute is wave-uniform (niter block-uniform).
__global__ __launch_bounds__(256, 2) void attn_kernel(
    const unsigned short* __restrict__ qg, const char* __restrict__ kT,
    const char* __restrict__ vT, float* __restrict__ out) {
  __shared__ char kls[2][2][8192];          // [stage-buf][tile-in-stage]
  __shared__ char vls[2][2][8192];
  __shared__ unsigned short ps[4][16][72];  // wave-private P^T [qrow][key]

  const int tid = threadIdx.x;
  const int h = tid >> 6, lane = tid & 63;
  const int lo = lane & 15, quad = lane >> 4;
  const int b = blockIdx.x & 15;
  const int idx = blockIdx.x >> 4;
  const int a = (blockIdx.x < 256) ? (31 - idx) : (idx - 16);
  const int j = 4 * a + h;
  const int niter = a + 1;
  const int nstage = (niter + 1) >> 1;
  const int qrow0 = j * 16;

  const unsigned short* qb = qg + (long)b * 2048 * 64;
  const char* kbT = kT + ((long)b * 32 << 13);
  const char* vbT = vT + ((long)b * 32 << 13);
  float* ob = out + (long)b * 2048 * 64;

  // Q fragments (B-operand), pre-scaled by 0.125*log2(e)
  const unsigned short* qr = qb + (long)(qrow0 + lo) * 64 + quad * 8;
  const bf16x8 bq0 = *(const bf16x8*)qr;
  const bf16x8 bq1 = *(const bf16x8*)(qr + 32);

  // prologue DMA: stage 0 (tiles 0,1 — always exist; 32 tiles/batch) -> buf 0
#pragma unroll
  for (int tt = 0; tt < 2; ++tt) {
    const char* kg = kbT + ((long)tt << 13);
    const char* vg = vbT + ((long)tt << 13);
#pragma unroll
    for (int s2 = 0; s2 < 2; ++s2) {
      const int s = h * 2 + s2;
      dma16(kg + s * 1024 + lane * 16, &kls[0][tt][s * 1024]);
      dma16(vg + s * 1024 + lane * 16, &vls[0][tt][s * 1024]);
    }
  }

  f32x4 oacc[4];
#pragma unroll
  for (int dt = 0; dt < 4; ++dt) oacc[dt] = (f32x4){0.f, 0.f, 0.f, 0.f};
  float l = 0.f;
  const int swz = (lo & 7);
  const int qrl = qrow0 + lo;

  for (int st = 0; st < nstage; ++st) {
    const int buf = st & 1;
    __syncthreads();  // stage st resident (vmcnt drained); buf^1 consumers done
    if (st + 1 < nstage) {
      // prefetch stage st+1 (tiles 2st+2, 2st+3; st+1 < nstage <= 16 -> tiles <= 31)
#pragma unroll
      for (int tt = 0; tt < 2; ++tt) {
        const int tn = 2 * st + 2 + tt;
        const char* kg = kbT + ((long)tn << 13);
        const char* vg = vbT + ((long)tn << 13);
#pragma unroll
        for (int s2 = 0; s2 < 2; ++s2) {
          const int s = h * 2 + s2;
          dma16(kg + s * 1024 + lane * 16, &kls[buf ^ 1][tt][s * 1024]);
          dma16(vg + s * 1024 + lane * 16, &vls[buf ^ 1][tt][s * 1024]);
        }
      }
    }
#pragma unroll
    for (int tt = 0; tt < 2; ++tt) {
      const int kt = 2 * st + tt;
      if (kt >= niter) break;             // wave-uniform (niter block-uniform)
      const bool diag = (kt == niter - 1);
      const int key0 = kt * 64;

      // per-16-key strip: QK -> mask -> exp2 -> pack -> ps
#pragma unroll
      for (int t = 0; t < 4; ++t) {
        const int row = (t * 16 + lo) * 128;
        bf16x8 ak0 = *(const bf16x8*)(&kls[buf][tt][row + ((quad ^ swz) << 4)]);
        bf16x8 ak1 = *(const bf16x8*)(&kls[buf][tt][row + (((4 + quad) ^ swz) << 4)]);
        f32x4 s = (f32x4){0.f, 0.f, 0.f, 0.f};
        s = mfma16(ak0, bq0, s);
        s = mfma16(ak1, bq1, s);
        if (diag) {
#pragma unroll
          for (int r = 0; r < 4; ++r)
            if (key0 + t * 16 + quad * 4 + r > qrl) s[r] = NEG_INF;
        }
        float e0 = __builtin_amdgcn_exp2f(s[0]);
        float e1 = __builtin_amdgcn_exp2f(s[1]);
        float e2 = __builtin_amdgcn_exp2f(s[2]);
        float e3 = __builtin_amdgcn_exp2f(s[3]);
        l += (e0 + e1) + (e2 + e3);
        uint2 uu;
        uu.x = pack2(e0, e1);
        uu.y = pack2(e2, e3);
        *(uint2*)&ps[h][lo][t * 16 + quad * 4] = uu;
      }
      asm volatile("s_waitcnt lgkmcnt(0)" ::: "memory");  // wave-private ps
      // O^T += V^T P^T
#pragma unroll
      for (int kk2 = 0; kk2 < 2; ++kk2) {
        bf16x8 bp = *(const bf16x8*)&ps[h][lo][kk2 * 32 + quad * 8];
#pragma unroll
        for (int dt = 0; dt < 4; ++dt) {
          const int rowv = (dt * 16 + lo) * 128;
          bf16x8 av =
              *(const bf16x8*)(&vls[buf][tt][rowv + (((kk2 * 4 + quad) ^ swz) << 4)]);
          oacc[dt] = mfma16(av, bp, oacc[dt]);
        }
      }
    }
  }

  // epilogue: per-wave complete rows — reduce l over quads, normalize, store
  l += __shfl_xor(l, 16, 64);
  l += __shfl_xor(l, 32, 64);
  const float inv = 1.0f / l;
  float* orow = ob + (long)(qrow0 + lo) * 64;
#pragma unroll
  for (int dt = 0; dt < 4; ++dt) {
    float4 st;
    st.x = oacc[dt][0] * inv; st.y = oacc[dt][1] * inv;
    st.z = oacc[dt][2] * inv; st.w = oacc[dt][3] * inv;
    *(float4*)(orow + dt * 16 + quad * 4) = st;
  }
}

// ---------------- launcher ----------------
extern "C" void kernel_launch(void* const* d_in, const int* in_sizes, int n_in,
                              void* d_out, int out_size, void* d_ws, size_t ws_size,
                              hipStream_t stream) {
  const float* x = (const float*)d_in[0];
  const float* wq = (const float*)d_in[1];
  const float* wk = (const float*)d_in[2];
  const float* wv = (const float*)d_in[3];
  float* out = (float*)d_out;

  char* ws = (char*)d_ws;
  char* wt = ws;                                   // 147456 B (6 chunks x 24576)
  const size_t MB4 = (size_t)4 * 1024 * 1024;      // 16*2048*64*2 bytes
  unsigned short* qws = (unsigned short*)(ws + 147456);
  char* kT = ws + 147456 + MB4;
  char* vT = ws + 147456 + 2 * MB4;

  prep_w<<<96, 256, 0, stream>>>(wq, wk, wv, wt);
  proj_kernel<<<512, 256, 0, stream>>>(x, wt, qws, kT, vT);
  attn_kernel<<<512, 256, 0, stream>>>(qws, kT, vT, out);
}